// Round 15
// baseline (145.837 us; speedup 1.0000x reference)
//
#include <hip/hip_runtime.h>
#include <math.h>

typedef float f32x4 __attribute__((ext_vector_type(4)));

// RBF constants: means = linspace(exp(-5), 1, 128); beta = (2/128*(1-exp(-5)))^-2
#define RBF_START 0.006737946999085467f
#define RBF_H     (0.993262053000915f / 127.0f)
#define RBF_INVH  (127.0f / 0.993262053000915f)
#define RBF_BETA  (1.0f / ((2.0f/128.0f*0.993262053000915f) * (2.0f/128.0f*0.993262053000915f)))
#define RBF_C2    (RBF_BETA * 1.44269504088896340736f)   // beta * log2(e)
#define KN 256          // knots: KN+1 samples of e in [0,1]; lerp err ~1e-6 on bias

// ---------------- kernel A: grid 257. Block g: bias-table knot g (pair layout);
// blocks 0..255 also compute padding mask for rows 8g..8g+7.
// tableP[k][h] = {T[h][k], T[h][k+1]}, stored as floats tb[k*64 + h*2 + {0,1}], k in 0..255.
__global__ __launch_bounds__(256) void prep_kernel(
    const float* __restrict__ nf, int* __restrict__ mask,
    const float* __restrict__ w1, const float* __restrict__ b1,
    const float* __restrict__ w2, const float* __restrict__ b2,
    float* __restrict__ tb) {
  int g = blockIdx.x, t = threadIdx.x;
  __shared__ float ef_s[128];
  __shared__ float ps2[256];
  __shared__ float hid_s[128];
  __shared__ int wany[8][4];

  // ---- table knot g ----
  float e = (float)g * (1.0f / (float)KN);
  if (t < 128) {
    float mu = fmaf((float)t, RBF_H, RBF_START);
    float diff = e - mu;
    ef_s[t] = __expf(-RBF_BETA * diff * diff);
  }
  __syncthreads();
  {   // GEMV split over 2 threads per hidden unit (k halves) -> half the serial chain
    int m = t & 127, half = t >> 7;
    float s = half ? 0.f : b1[m];
    const float* wp = w1 + (size_t)(half * 64) * 128 + m;
    const float* ep = ef_s + half * 64;
#pragma unroll
    for (int k = 0; k < 64; k++) s = fmaf(ep[k], wp[k * 128], s);
    ps2[t] = s;
  }
  __syncthreads();
  if (t < 128) {
    float s = ps2[t] + ps2[t + 128];
    hid_s[t] = 0.5f * s * (1.0f + erff(s * 0.70710678118654752f));  // exact GELU
  }
  __syncthreads();
  {
    int h = t >> 3, seg = t & 7;               // 32 heads x 8 segments
    float s = 0.f;
    const float* hp = hid_s + seg * 16;
    const float* wp = w2 + (seg * 16) * 32 + h;
#pragma unroll
    for (int m = 0; m < 16; m++) s = fmaf(hp[m], wp[m * 32], s);
    s += __shfl_xor(s, 1);
    s += __shfl_xor(s, 2);
    s += __shfl_xor(s, 4);
    if (seg == 0) {
      float v = s + b2[h];                     // T[h][g]
      if (g < 256) tb[g * 64 + h * 2 + 0] = v;           // .x of row g
      if (g > 0)   tb[(g - 1) * 64 + h * 2 + 1] = v;     // .y of row g-1
    }
  }

  // ---- padding mask rows 8g..8g+7 ----
  if (g < 256) {
#pragma unroll
    for (int r = 0; r < 8; r++) {
      const float* p = nf + (size_t)(g * 8 + r) * 768;
      bool nz = (p[t] != 0.f) || (p[t + 256] != 0.f) || (p[t + 512] != 0.f);
      unsigned long long bal = __ballot(nz);
      if ((t & 63) == 0) wany[r][t >> 6] = (bal != 0ull);
    }
    __syncthreads();
    if (t < 8)
      mask[g * 8 + t] = (wany[t][0] | wany[t][1] | wany[t][2] | wany[t][3]) ? 0 : 1;
  }
}

// ---------------- kernel B: fused per-pair kernel, 2048 wg, ~2 KB LDS ----------------
// R12 structure; stage-2 (lerp + 16 independent out0 stores) AFTER the e_s barrier in
// the same scheduling region as stage-3, so the compiler interleaves store issue +
// lerp VALU into the exp loop's trans-pipe stalls. exp2-folded RBF (exp2f == v_exp_f32).
__global__ __launch_bounds__(256) void main_kernel(
    const float* __restrict__ pos, const int* __restrict__ mask,
    const float* __restrict__ tb,
    float* __restrict__ out0, float* __restrict__ out2,
    float* __restrict__ part) {
  __shared__ float e_s[256];
  __shared__ float ps[2][128];
  int t = threadIdx.x, g = blockIdx.x;
  int b = g >> 8, i = g & 255;

  // stage 1: distance, e = exp(-d), delta_pos out, e_s
  int j = t;
  const float* pb = pos + b * 768;
  float dx = pb[i * 3 + 0] - pb[j * 3 + 0];
  float dy = pb[i * 3 + 1] - pb[j * 3 + 1];
  float dz = pb[i * 3 + 2] - pb[j * 3 + 2];
  float r2 = dx * dx + dy * dy + dz * dz;
  float d = (r2 > 0.f) ? sqrtf(r2) : 0.f;
  float e = __expf(-d);                        // ALPHA=1, CUT_LO=0
  size_t base2 = ((size_t)g * 256 + (size_t)j) * 3;
  out2[base2 + 0] = dx; out2[base2 + 1] = dy; out2[base2 + 2] = dz;

  bool pad = mask[b * 256 + j] != 0;
  e_s[j] = pad ? 3.0f : e;                     // sentinel: exp2(-C2*(3-mu)^2) == 0

  __syncthreads();                             // e_s ready

  // stage 2+3 fused region: stores/lerps interleave with the exp loop
  {
    float u = e * (float)KN;
    int i0 = (int)u; i0 = min(i0, KN - 1);
    float fr = u - (float)i0;
    const f32x4* tp4 = (const f32x4*)(tb + (size_t)i0 * 64);
    size_t ob = (size_t)b * 2097152 + (size_t)i * 256 + (size_t)j;
#pragma unroll
    for (int r = 0; r < 8; r++) {
      f32x4 pr = tp4[r];                       // {T[2r].x, T[2r].y, T[2r+1].x, T[2r+1].y}
      float v0 = fmaf(fr, pr[1] - pr[0], pr[0]);
      float v1 = fmaf(fr, pr[3] - pr[2], pr[2]);
      out0[ob + (size_t)(2 * r) * 65536]     = pad ? -1e20f : v0;
      out0[ob + (size_t)(2 * r + 1) * 65536] = pad ? -1e20f : v1;
    }

    int k = t & 127, half = t >> 7;
    float mu = fmaf((float)k, RBF_H, RBF_START);
    float s = 0.f;
    const f32x4* ev = (const f32x4*)&e_s[half * 128];
#pragma unroll 8
    for (int q4 = 0; q4 < 32; q4++) {
      f32x4 e4 = ev[q4];                       // wave-uniform addr -> LDS broadcast
#pragma unroll
      for (int q = 0; q < 4; q++) {
        float df = e4[q] - mu;
        s += exp2f(-RBF_C2 * df * df);         // v_exp_f32; out-of-band underflows to 0
      }
    }
    ps[half][k] = s;
  }
  __syncthreads();
  if (t < 128) part[(size_t)g * 128 + t] = ps[0][t] + ps[1][t];
}

// ---------------- kernel C: merge = part @ ew + eb. 1024-thr blocks (R13-proven) ----------------
__global__ __launch_bounds__(1024) void merge_kernel(const float* __restrict__ part,
                                                     const float* __restrict__ ew,
                                                     const float* __restrict__ eb,
                                                     float* __restrict__ out1) {
  __shared__ float s_s[8][128];
  int t = threadIdx.x;
  int r0 = blockIdx.x * 8;
  {
    int row = t >> 7, k = t & 127;             // 1024 = 8*128: one load each
    s_s[row][k] = part[(size_t)(r0 + row) * 128 + k];
  }
  __syncthreads();

  int q = t >> 8, o = t & 255;
  float acc[3][2];
#pragma unroll
  for (int c = 0; c < 3; c++) { acc[c][0] = 0.f; acc[c][1] = 0.f; }

#pragma unroll 4
  for (int k = 0; k < 128; k++) {
    float w0 = ew[k * 768 + o];
    float w1v = ew[k * 768 + 256 + o];
    float w2v = ew[k * 768 + 512 + o];
    float s0 = s_s[q * 2 + 0][k];              // wave-uniform -> LDS broadcast
    float s1 = s_s[q * 2 + 1][k];
    acc[0][0] = fmaf(s0, w0, acc[0][0]);  acc[0][1] = fmaf(s1, w0, acc[0][1]);
    acc[1][0] = fmaf(s0, w1v, acc[1][0]); acc[1][1] = fmaf(s1, w1v, acc[1][1]);
    acc[2][0] = fmaf(s0, w2v, acc[2][0]); acc[2][1] = fmaf(s1, w2v, acc[2][1]);
  }

#pragma unroll
  for (int c = 0; c < 3; c++) {
    float ebv = eb[c * 256 + o];
#pragma unroll
    for (int r2 = 0; r2 < 2; r2++)
      out1[(size_t)(r0 + q * 2 + r2) * 768 + c * 256 + o] = acc[c][r2] + ebv;
  }
}

// ---------------- launch ----------------
extern "C" void kernel_launch(void* const* d_in, const int* in_sizes, int n_in,
                              void* d_out, int out_size, void* d_ws, size_t ws_size,
                              hipStream_t stream) {
    const float* nf    = (const float*)d_in[0];
    const float* pos   = (const float*)d_in[1];
    const float* w1    = (const float*)d_in[4];
    const float* b1    = (const float*)d_in[5];
    const float* w2    = (const float*)d_in[6];
    const float* b2    = (const float*)d_in[7];
    const float* ew    = (const float*)d_in[8];
    const float* eb    = (const float*)d_in[9];

    float* out0 = (float*)d_out;                         // [8,32,256,256]
    float* out1 = out0 + (size_t)8 * 32 * 256 * 256;     // [8,256,768]
    float* out2 = out1 + (size_t)8 * 256 * 768;          // [8,256,256,3]

    char* ws = (char*)d_ws;
    int*    mask   = (int*)ws;                           // 8 KB
    float*  tb     = (float*)(ws + 8192);                // pair table: 256*64*4 = 64 KB
    float*  part   = (float*)(ws + 81920);               // 2048*128*4 = 1 MB

    hipLaunchKernelGGL(prep_kernel,  dim3(257),  dim3(256), 0, stream,
                       nf, mask, w1, b1, w2, b2, tb);
    hipLaunchKernelGGL(main_kernel,  dim3(2048), dim3(256), 0, stream,
                       pos, mask, tb, out0, out2, part);
    hipLaunchKernelGGL(merge_kernel, dim3(256),  dim3(1024), 0, stream, part, ew, eb, out1);
}

// Round 16
// 136.922 us; speedup vs baseline: 1.0651x; 1.0651x over previous
//
#include <hip/hip_runtime.h>
#include <math.h>

typedef float f32x4 __attribute__((ext_vector_type(4)));

// RBF constants: means = linspace(exp(-5), 1, 128); beta = (2/128*(1-exp(-5)))^-2
#define RBF_START 0.006737946999085467f
#define RBF_H     (0.993262053000915f / 127.0f)
#define RBF_INVH  (127.0f / 0.993262053000915f)
#define RBF_BETA  (1.0f / ((2.0f/128.0f*0.993262053000915f) * (2.0f/128.0f*0.993262053000915f)))
#define KN 256          // knots: KN+1 samples of e in [0,1]; lerp err ~1e-6 on bias

// ---------------- kernel A: grid 257. Block g: bias-table knot g (pair layout);
// blocks 0..255 also compute padding mask for rows 8g..8g+7.
// tableP[k][h] = {T[h][k], T[h][k+1]}, stored as floats tb[k*64 + h*2 + {0,1}], k in 0..255.
// GEMV split over 2 threads per hidden unit (k halves) halves the serial fma chain.
__global__ __launch_bounds__(256) void prep_kernel(
    const float* __restrict__ nf, int* __restrict__ mask,
    const float* __restrict__ w1, const float* __restrict__ b1,
    const float* __restrict__ w2, const float* __restrict__ b2,
    float* __restrict__ tb) {
  int g = blockIdx.x, t = threadIdx.x;
  __shared__ float ef_s[128];
  __shared__ float ps2[256];
  __shared__ float hid_s[128];
  __shared__ int wany[8][4];

  // ---- table knot g ----
  float e = (float)g * (1.0f / (float)KN);
  if (t < 128) {
    float mu = fmaf((float)t, RBF_H, RBF_START);
    float diff = e - mu;
    ef_s[t] = __expf(-RBF_BETA * diff * diff);
  }
  __syncthreads();
  {   // GEMV split over 2 threads per hidden unit (k halves)
    int m = t & 127, half = t >> 7;
    float s = half ? 0.f : b1[m];
    const float* wp = w1 + (size_t)(half * 64) * 128 + m;
    const float* ep = ef_s + half * 64;
#pragma unroll
    for (int k = 0; k < 64; k++) s = fmaf(ep[k], wp[k * 128], s);
    ps2[t] = s;
  }
  __syncthreads();
  if (t < 128) {
    float s = ps2[t] + ps2[t + 128];
    hid_s[t] = 0.5f * s * (1.0f + erff(s * 0.70710678118654752f));  // exact GELU
  }
  __syncthreads();
  {
    int h = t >> 3, seg = t & 7;               // 32 heads x 8 segments
    float s = 0.f;
    const float* hp = hid_s + seg * 16;
    const float* wp = w2 + (seg * 16) * 32 + h;
#pragma unroll
    for (int m = 0; m < 16; m++) s = fmaf(hp[m], wp[m * 32], s);
    s += __shfl_xor(s, 1);
    s += __shfl_xor(s, 2);
    s += __shfl_xor(s, 4);
    if (seg == 0) {
      float v = s + b2[h];                     // T[h][g]
      if (g < 256) tb[g * 64 + h * 2 + 0] = v;           // .x of row g
      if (g > 0)   tb[(g - 1) * 64 + h * 2 + 1] = v;     // .y of row g-1
    }
  }

  // ---- padding mask rows 8g..8g+7 ----
  if (g < 256) {
#pragma unroll
    for (int r = 0; r < 8; r++) {
      const float* p = nf + (size_t)(g * 8 + r) * 768;
      bool nz = (p[t] != 0.f) || (p[t + 256] != 0.f) || (p[t + 512] != 0.f);
      unsigned long long bal = __ballot(nz);
      if ((t & 63) == 0) wany[r][t >> 6] = (bal != 0ull);
    }
    __syncthreads();
    if (t < 8)
      mask[g * 8 + t] = (wany[t][0] | wany[t][1] | wany[t][2] | wany[t][3]) ? 0 : 1;
  }
}

// ---------------- kernel B: fused per-pair kernel, 2048 wg, ~2 KB LDS ----------------
// EXACT R13 structure (best measured): stage-2 stores issue BEFORE the e_s barrier
// (overlap the barrier wait), stage-3 atomic-free transposed reduction with __expf.
__global__ __launch_bounds__(256) void main_kernel(
    const float* __restrict__ pos, const int* __restrict__ mask,
    const float* __restrict__ tb,
    float* __restrict__ out0, float* __restrict__ out2,
    float* __restrict__ part) {
  __shared__ float e_s[256];
  __shared__ float ps[2][128];
  int t = threadIdx.x, g = blockIdx.x;
  int b = g >> 8, i = g & 255;

  // stage 1: distance, e = exp(-d), delta_pos out, e_s
  int j = t;
  const float* pb = pos + b * 768;
  float dx = pb[i * 3 + 0] - pb[j * 3 + 0];
  float dy = pb[i * 3 + 1] - pb[j * 3 + 1];
  float dz = pb[i * 3 + 2] - pb[j * 3 + 2];
  float r2 = dx * dx + dy * dy + dz * dz;
  float d = (r2 > 0.f) ? sqrtf(r2) : 0.f;
  float e = __expf(-d);                        // ALPHA=1, CUT_LO=0
  size_t base2 = ((size_t)g * 256 + (size_t)j) * 3;
  out2[base2 + 0] = dx; out2[base2 + 1] = dy; out2[base2 + 2] = dz;

  bool pad = mask[b * 256 + j] != 0;
  e_s[j] = pad ? 3.0f : e;                     // sentinel: beta*(3-mu)^2 > 1000 -> exp = 0

  // stage 2: 32-head bias, one pair-row load + register lerps (pre-barrier: overlaps wait)
  {
    float u = e * (float)KN;
    int i0 = (int)u; i0 = min(i0, KN - 1);
    float fr = u - (float)i0;
    const f32x4* tp4 = (const f32x4*)(tb + (size_t)i0 * 64);
    size_t ob = (size_t)b * 2097152 + (size_t)i * 256 + (size_t)j;
#pragma unroll
    for (int r = 0; r < 8; r++) {
      f32x4 pr = tp4[r];                       // {T[2r].x, T[2r].y, T[2r+1].x, T[2r+1].y}
      float v0 = fmaf(fr, pr[1] - pr[0], pr[0]);
      float v1 = fmaf(fr, pr[3] - pr[2], pr[2]);
      out0[ob + (size_t)(2 * r) * 65536]     = pad ? -1e20f : v0;
      out0[ob + (size_t)(2 * r + 1) * 65536] = pad ? -1e20f : v1;
    }
  }

  // stage 3: atomic-free transposed column sums
  __syncthreads();                             // e_s ready
  {
    int k = t & 127, half = t >> 7;
    float mu = fmaf((float)k, RBF_H, RBF_START);
    float s = 0.f;
    const f32x4* ev = (const f32x4*)&e_s[half * 128];
#pragma unroll 8
    for (int q4 = 0; q4 < 32; q4++) {
      f32x4 e4 = ev[q4];                       // wave-uniform addr -> LDS broadcast
#pragma unroll
      for (int q = 0; q < 4; q++) {
        float df = e4[q] - mu;
        s += __expf(-RBF_BETA * df * df);      // out-of-band underflows to 0
      }
    }
    ps[half][k] = s;
  }
  __syncthreads();
  if (t < 128) part[(size_t)g * 128 + t] = ps[0][t] + ps[1][t];
}

// ---------------- kernel C: merge = part @ ew + eb. 1024-thr blocks (R13-proven) ----------------
__global__ __launch_bounds__(1024) void merge_kernel(const float* __restrict__ part,
                                                     const float* __restrict__ ew,
                                                     const float* __restrict__ eb,
                                                     float* __restrict__ out1) {
  __shared__ float s_s[8][128];
  int t = threadIdx.x;
  int r0 = blockIdx.x * 8;
  {
    int row = t >> 7, k = t & 127;             // 1024 = 8*128: one load each
    s_s[row][k] = part[(size_t)(r0 + row) * 128 + k];
  }
  __syncthreads();

  int q = t >> 8, o = t & 255;
  float acc[3][2];
#pragma unroll
  for (int c = 0; c < 3; c++) { acc[c][0] = 0.f; acc[c][1] = 0.f; }

#pragma unroll 4
  for (int k = 0; k < 128; k++) {
    float w0 = ew[k * 768 + o];
    float w1v = ew[k * 768 + 256 + o];
    float w2v = ew[k * 768 + 512 + o];
    float s0 = s_s[q * 2 + 0][k];              // wave-uniform -> LDS broadcast
    float s1 = s_s[q * 2 + 1][k];
    acc[0][0] = fmaf(s0, w0, acc[0][0]);  acc[0][1] = fmaf(s1, w0, acc[0][1]);
    acc[1][0] = fmaf(s0, w1v, acc[1][0]); acc[1][1] = fmaf(s1, w1v, acc[1][1]);
    acc[2][0] = fmaf(s0, w2v, acc[2][0]); acc[2][1] = fmaf(s1, w2v, acc[2][1]);
  }

#pragma unroll
  for (int c = 0; c < 3; c++) {
    float ebv = eb[c * 256 + o];
#pragma unroll
    for (int r2 = 0; r2 < 2; r2++)
      out1[(size_t)(r0 + q * 2 + r2) * 768 + c * 256 + o] = acc[c][r2] + ebv;
  }
}

// ---------------- launch ----------------
extern "C" void kernel_launch(void* const* d_in, const int* in_sizes, int n_in,
                              void* d_out, int out_size, void* d_ws, size_t ws_size,
                              hipStream_t stream) {
    const float* nf    = (const float*)d_in[0];
    const float* pos   = (const float*)d_in[1];
    const float* w1    = (const float*)d_in[4];
    const float* b1    = (const float*)d_in[5];
    const float* w2    = (const float*)d_in[6];
    const float* b2    = (const float*)d_in[7];
    const float* ew    = (const float*)d_in[8];
    const float* eb    = (const float*)d_in[9];

    float* out0 = (float*)d_out;                         // [8,32,256,256]
    float* out1 = out0 + (size_t)8 * 32 * 256 * 256;     // [8,256,768]
    float* out2 = out1 + (size_t)8 * 256 * 768;          // [8,256,256,3]

    char* ws = (char*)d_ws;
    int*    mask   = (int*)ws;                           // 8 KB
    float*  tb     = (float*)(ws + 8192);                // pair table: 256*64*4 = 64 KB
    float*  part   = (float*)(ws + 81920);               // 2048*128*4 = 1 MB

    hipLaunchKernelGGL(prep_kernel,  dim3(257),  dim3(256), 0, stream,
                       nf, mask, w1, b1, w2, b2, tb);
    hipLaunchKernelGGL(main_kernel,  dim3(2048), dim3(256), 0, stream,
                       pos, mask, tb, out0, out2, part);
    hipLaunchKernelGGL(merge_kernel, dim3(256),  dim3(1024), 0, stream, part, ew, eb, out1);
}